// Round 11
// baseline (228.257 us; speedup 1.0000x reference)
//
#include <hip/hip_runtime.h>
#include <hip/hip_bf16.h>

#define BB 65536
#define NFIELD 20
#define HID 64
#define KEXP 16
#define EPS 1e-5f
#define KPAD 224
#define NKS 7            // 224/32 K-steps
#define NBLK_GATE 1024   // 64 samples per gate block
#define NBX_EXP 80
#define TSTR 228         // gate LDS tile stride (bf16) -> 2-way max bank aliasing

typedef __attribute__((ext_vector_type(8))) short v8s;   // 8 bf16
typedef __attribute__((ext_vector_type(4))) float v4f;
typedef __attribute__((ext_vector_type(2))) float v2f;

// ---- ws layout (4B element offsets) ----
#define OFF_GCNT 0
#define OFF_SC1 64
#define OFF_SH1 1088
#define OFF_SC2 2112
#define OFF_SH2 3136
#define OFF_SCP 4160
#define OFF_SHP 4224
#define OFF_IMP 4288            // 1024*16 f32
#define OFF_LIDX 20672          // 16*BB int
#define OFF_LW  1069248         // 16*BB f32
#define OFF_W1T 2117824         // 16*64*224 bf16
#define OFF_GW1T 2232512        // 64*224 bf16
#define OFF_W2T 2239680         // 16*64*64 bf16
#define OFF_PW1T 2272448        // 64*64 bf16
#define OFF_XEMB 2274496        // 65537*224 bf16
#define OFF_HS 9614640          // 131073*64 bf16

__device__ __forceinline__ unsigned short f2bf(float f) {
    unsigned int u = __float_as_uint(f);
    unsigned int r = (u + 0x7FFFu + ((u >> 16) & 1u)) >> 16;
    return (unsigned short)r;
}
__device__ __forceinline__ float bf2f(unsigned short u) {
    unsigned int t = ((unsigned int)u) << 16;
    return __uint_as_float(t);
}
__device__ __forceinline__ unsigned int pack2(float a, float b) {
    return (unsigned int)f2bf(a) | ((unsigned int)f2bf(b) << 16);
}

// ---------------- prep: BN folds + bf16 weight transposes + gcnt zero ----------------
__global__ __launch_bounds__(256) void k_prep(
    const float* __restrict__ ew1, const float* __restrict__ ew2,
    const float* __restrict__ gw1, const float* __restrict__ pw1,
    const float* __restrict__ eb1, const float* __restrict__ eg1,
    const float* __restrict__ ebe1, const float* __restrict__ em1,
    const float* __restrict__ ev1,
    const float* __restrict__ eb2, const float* __restrict__ eg2,
    const float* __restrict__ ebe2, const float* __restrict__ em2,
    const float* __restrict__ ev2,
    const float* __restrict__ pb1, const float* __restrict__ pg,
    const float* __restrict__ pbe, const float* __restrict__ pm,
    const float* __restrict__ pv,
    float* __restrict__ wsf, int* __restrict__ gcnt,
    unsigned short* __restrict__ w1t, unsigned short* __restrict__ gw1t,
    unsigned short* __restrict__ w2t, unsigned short* __restrict__ pw1t)
{
    int gid = blockIdx.x * 256 + threadIdx.x;
    if (gid < 229376) {               // W1T[k][c][t] = ew1[k][t][c]
        int k = gid / 14336, r = gid % 14336, c = r / KPAD, t = r % KPAD;
        w1t[gid] = (t < 200) ? f2bf(ew1[((size_t)k * 200 + t) * HID + c]) : 0;
    } else if (gid < 229376 + 14336) { // gw1T[c][t]
        int g2 = gid - 229376; int c = g2 / KPAD, t = g2 % KPAD;
        gw1t[g2] = (t < 200) ? f2bf(gw1[t * HID + c]) : 0;
    } else if (gid < 243712 + 65536) { // W2T[k][g][i] = ew2[k][i][g]
        int g2 = gid - 243712; int k = g2 / 4096, r = g2 % 4096, g = r / 64, i = r % 64;
        w2t[g2] = f2bf(ew2[((size_t)k * 64 + i) * 64 + g]);
    } else if (gid < 309248 + 4096) {  // PW1T[g][i] = pw1[i][g]
        int g2 = gid - 309248; int g = g2 / 64, i = g2 % 64;
        pw1t[g2] = f2bf(pw1[i * 64 + g]);
    } else if (gid < 313344 + 1024) {
        int t = gid - 313344;
        float rs1 = rsqrtf(ev1[t] + EPS) * eg1[t];
        wsf[OFF_SC1 + t] = rs1;
        wsf[OFF_SH1 + t] = fmaf(eb1[t] - em1[t], rs1, ebe1[t]);
        float rs2 = rsqrtf(ev2[t] + EPS) * eg2[t];
        wsf[OFF_SC2 + t] = rs2;
        wsf[OFF_SH2 + t] = fmaf(eb2[t] - em2[t], rs2, ebe2[t]);
    } else if (gid < 314368 + 64) {
        int t = gid - 314368;
        float rs = rsqrtf(pv[t] + EPS) * pg[t];
        wsf[OFF_SCP + t] = rs;
        wsf[OFF_SHP + t] = fmaf(pb1[t] - pm[t], rs, pbe[t]);
    } else if (gid < 314432 + 16) {
        gcnt[gid - 314432] = 0;
    }
}

// ---------------- fused gather+gate (256 thr, nt loads, deep MLP) ----------------
__global__ __launch_bounds__(256) void k_gate(
    const int* __restrict__ x, const int* __restrict__ sql,
    const float* __restrict__ itab, const float* __restrict__ stab,
    const unsigned short* __restrict__ gw1t,
    const float* __restrict__ gb1, const float* __restrict__ gw2,
    const float* __restrict__ gb2,
    unsigned short* __restrict__ xembT,
    int* __restrict__ lidx, float* __restrict__ lw,
    int* __restrict__ gcnt, float* __restrict__ imp_part)
{
    __shared__ unsigned short tile[64][TSTR];       // 29184 B; Hg overlaid after MFMA
    __shared__ float s_imp[KEXP];
    __shared__ int s_cnt[KEXP];
    __shared__ int s_base[KEXP];
    unsigned short (*Hg)[80] = (unsigned short (*)[80])&tile[0][0];
    int tid = threadIdx.x;
    int wid = tid >> 6, l = tid & 63;
    int m = l & 15, q = l >> 4;
    int b0 = blockIdx.x * 64;

    if (tid < KEXP) { s_imp[tid] = 0.f; s_cnt[tid] = 0; }
    // zero pad cols 200..223 of sql LDS tile
    for (int t = tid; t < 64 * 12; t += 256) {
        int r = t / 12, c2 = t % 12;
        *(unsigned int*)&tile[r][200 + 2 * c2] = 0;
    }
    // zero xembT tail cols 200..223 (bytes 400..447 of each 448B row)
    {
        uint4 z4 = {0u, 0u, 0u, 0u};
        if (tid < 192) {
            int row = tid / 3, j = tid % 3;
            *(uint4*)((char*)(xembT + (size_t)(b0 + row) * KPAD) + 400 + 16 * j) = z4;
        }
    }
    // ---- gather: 64*20 row-pairs, 5 per thread; all indices then all rows (nt) ----
    {
        int sidx[5], xidx[5];
#pragma unroll
        for (int rr = 0; rr < 5; ++rr) {
            int r = tid + rr * 256;                           // (b0+lb)*20+f == b0*20+r
            sidx[rr] = sql[(size_t)b0 * NFIELD + r];
            xidx[rr] = x[(size_t)b0 * NFIELD + r];
        }
        v4f sA[5], sB[5]; v2f sC[5];
        v4f xA[5], xB[5]; v2f xC[5];
#pragma unroll
        for (int rr = 0; rr < 5; ++rr) {
            const float* srow = stab + (size_t)sidx[rr] * 10;
            sA[rr] = __builtin_nontemporal_load((const v4f*)(srow + 0));
            sB[rr] = __builtin_nontemporal_load((const v4f*)(srow + 4));
            sC[rr] = __builtin_nontemporal_load((const v2f*)(srow + 8));
        }
#pragma unroll
        for (int rr = 0; rr < 5; ++rr) {
            const float* xrow = itab + (size_t)xidx[rr] * 10;
            xA[rr] = __builtin_nontemporal_load((const v4f*)(xrow + 0));
            xB[rr] = __builtin_nontemporal_load((const v4f*)(xrow + 4));
            xC[rr] = __builtin_nontemporal_load((const v2f*)(xrow + 8));
        }
#pragma unroll
        for (int rr = 0; rr < 5; ++rr) {
            int r = tid + rr * 256;
            int lb = r / NFIELD, f = r % NFIELD;
            unsigned int* lrow = (unsigned int*)&tile[lb][f * 10];
            lrow[0] = pack2(sA[rr].x, sA[rr].y);
            lrow[1] = pack2(sA[rr].z, sA[rr].w);
            lrow[2] = pack2(sB[rr].x, sB[rr].y);
            lrow[3] = pack2(sB[rr].z, sB[rr].w);
            lrow[4] = pack2(sC[rr].x, sC[rr].y);
        }
#pragma unroll
        for (int rr = 0; rr < 5; ++rr) {
            int r = tid + rr * 256;
            int lb = r / NFIELD, f = r % NFIELD;
            unsigned int* grow = (unsigned int*)(xembT + (size_t)(b0 + lb) * KPAD + f * 10);
            uint4 g0;
            g0.x = pack2(xA[rr].x, xA[rr].y);
            g0.y = pack2(xA[rr].z, xA[rr].w);
            g0.z = pack2(xB[rr].x, xB[rr].y);
            g0.w = pack2(xB[rr].z, xB[rr].w);
            *(uint4*)grow = g0;
            grow[4] = pack2(xC[rr].x, xC[rr].y);
        }
    }
    __syncthreads();

    // MFMA: 64 samples x 16 cols (this wave) x K=224
    v4f zero4 = {0.f, 0.f, 0.f, 0.f};
    v4f acc[4];
#pragma unroll
    for (int a = 0; a < 4; ++a) acc[a] = zero4;
    const unsigned short* Bb = gw1t + (wid * 16 + m) * KPAD + q * 8;
#pragma unroll
    for (int Ks = 0; Ks < NKS; ++Ks) {
        v8s bv = *(const v8s*)(Bb + Ks * 32);
        v8s a[4];
#pragma unroll
        for (int Mt = 0; Mt < 4; ++Mt)
            a[Mt] = *(const v8s*)&tile[Mt * 16 + m][Ks * 32 + q * 8];
#pragma unroll
        for (int Mt = 0; Mt < 4; ++Mt)
            acc[Mt] = __builtin_amdgcn_mfma_f32_16x16x32_bf16(a[Mt], bv, acc[Mt], 0, 0, 0);
    }
    __syncthreads();   // all tile reads done before Hg overlay

    int c = wid * 16 + m;
    float bias = gb1[c];
#pragma unroll
    for (int Mt = 0; Mt < 4; ++Mt)
#pragma unroll
        for (int j = 0; j < 4; ++j) {
            int item = Mt * 16 + q * 4 + j;
            float v = fmaxf(acc[Mt][j] + bias, 0.f);
            Hg[item][c ^ ((item & 7) << 3)] = f2bf(v);
        }
    __syncthreads();   // Hg ready

    if (wid == 0) {
        float z[KEXP];
#pragma unroll
        for (int j = 0; j < KEXP; ++j) z[j] = gb2[j];
#pragma unroll
        for (int u = 0; u < 8; ++u) {
            v8s hv = *(const v8s*)&Hg[l][(u * 8) ^ ((l & 7) << 3)];
#pragma unroll
            for (int e = 0; e < 8; ++e) {
                int h = u * 8 + e;
                float g = bf2f((unsigned short)hv[e]);
#pragma unroll
                for (int j = 0; j < KEXP; ++j) z[j] = fmaf(g, gw2[h * KEXP + j], z[j]);
            }
        }
        float mm = z[0];
#pragma unroll
        for (int j = 1; j < KEXP; ++j) mm = fmaxf(mm, z[j]);
        float s = 0.f;
#pragma unroll
        for (int j = 0; j < KEXP; ++j) s += expf(z[j] - mm);
        int i0 = 0; float m0 = z[0];
#pragma unroll
        for (int j = 1; j < KEXP; ++j) if (z[j] > m0) { m0 = z[j]; i0 = j; }
        int i1 = (i0 == 0) ? 1 : 0; float m1 = -3.4e38f;
#pragma unroll
        for (int j = 0; j < KEXP; ++j) if (j != i0 && z[j] > m1) { m1 = z[j]; i1 = j; }
        float v0 = expf(m0 - mm) / s, v1 = expf(m1 - mm) / s;
        float inv = 1.f / (v0 + v1 + 1e-9f);
        float w0 = v0 * inv, w1 = v1 * inv;

        atomicAdd(&s_imp[i0], w0);
        atomicAdd(&s_imp[i1], w1);
        int o0 = atomicAdd(&s_cnt[i0], 1);
        int o1 = atomicAdd(&s_cnt[i1], 1);
        __syncthreads();   // wave0 atomics visible
        if (l < KEXP) s_base[l] = atomicAdd(&gcnt[l], s_cnt[l]);
        __syncthreads();
        int b = b0 + l;
        int p0 = i0 * BB + s_base[i0] + o0;
        lidx[p0] = (b << 1);     lw[p0] = w0;
        int p1 = i1 * BB + s_base[i1] + o1;
        lidx[p1] = (b << 1) | 1; lw[p1] = w1;
    } else {
        __syncthreads();
        __syncthreads();
    }
    __syncthreads();
    if (tid < KEXP) imp_part[blockIdx.x * KEXP + tid] = s_imp[tid];
}

// ---------------- pad each expert list to multiple of 64 with benign entries ----------------
__global__ void k_pad(const int* __restrict__ gcnt, int* __restrict__ lidx,
                      float* __restrict__ lw)
{
    int k = blockIdx.x;
    int n = gcnt[k];
    int ne = (n + 63) & ~63;
    for (int i = n + threadIdx.x; i < ne; i += 64) {
        lidx[k * BB + i] = 2 * BB;   // dedicated pad row
        lw[k * BB + i] = 0.f;
    }
}

// ---------------- loss ----------------
__global__ __launch_bounds__(256) void k_loss(const float* __restrict__ imp_part,
                                              float* __restrict__ out)
{
    __shared__ double sred[16][17];
    __shared__ double simp[KEXP];
    int tid = threadIdx.x;
    int j = tid & 15, g = tid >> 4;
    double s = 0.0;
    for (int blk = g; blk < NBLK_GATE; blk += 16) s += (double)imp_part[blk * KEXP + j];
    sred[g][j] = s;
    __syncthreads();
    if (tid < KEXP) {
        double t = 0.0;
#pragma unroll
        for (int gg = 0; gg < 16; ++gg) t += sred[gg][tid];
        simp[tid] = t;
    }
    __syncthreads();
    if (tid == 0) {
        double mean = 0.0;
        for (int jj = 0; jj < KEXP; ++jj) mean += simp[jj];
        mean /= KEXP;
        double var = 0.0;
        for (int jj = 0; jj < KEXP; ++jj) { double d = simp[jj] - mean; var += d * d; }
        var /= KEXP;
        out[BB] = (float)(var / (mean * mean + 1e-10));
    }
}

// ---------------- fused expert: MFMA L1 -> LDS -> MFMA L2 -> hs (bf16) ----------------
__global__ __launch_bounds__(256, 2) void k_exp(
    const unsigned short* __restrict__ xembT,
    const unsigned short* __restrict__ w1t, const unsigned short* __restrict__ w2t,
    const float* __restrict__ sc1, const float* __restrict__ sh1,
    const float* __restrict__ sc2, const float* __restrict__ sh2,
    const int* __restrict__ lidx, const float* __restrict__ lw,
    const int* __restrict__ gcnt, unsigned short* __restrict__ hs)
{
    __shared__ unsigned short Hl[4][64][80];   // 40960 B, bank-rotating rows
    int k = blockIdx.y;
    int tid = threadIdx.x;
    int wid = tid >> 6, l = tid & 63;
    int m = l & 15, q = l >> 4;
    int n = gcnt[k];
    int ne = (n + 63) & ~63;
    const unsigned short* W1 = w1t + (size_t)k * 64 * KPAD + m * KPAD + q * 8;
    const unsigned short* W2 = w2t + (size_t)k * 64 * 64 + m * 64 + q * 8;
    float sc1v[4], sh1v[4], sc2v[4], sh2v[4];
#pragma unroll
    for (int Nt = 0; Nt < 4; ++Nt) {
        int c = Nt * 16 + m;
        sc1v[Nt] = sc1[k * HID + c]; sh1v[Nt] = sh1[k * HID + c];
        sc2v[Nt] = sc2[k * HID + c]; sh2v[Nt] = sh2[k * HID + c];
    }
    v4f zero4 = {0.f, 0.f, 0.f, 0.f};

    for (int it0 = (blockIdx.x * 4 + wid) * 64; it0 < ne; it0 += NBX_EXP * 256) {
        // ---- layer 1 ----
        int eA[4];
#pragma unroll
        for (int Mt = 0; Mt < 4; ++Mt) eA[Mt] = lidx[k * BB + it0 + Mt * 16 + m];
        v4f acc1[4][4];
#pragma unroll
        for (int a = 0; a < 4; ++a)
#pragma unroll
            for (int c = 0; c < 4; ++c) acc1[a][c] = zero4;
#pragma unroll
        for (int Ks = 0; Ks < NKS; ++Ks) {
            v8s a[4], b[4];
#pragma unroll
            for (int Mt = 0; Mt < 4; ++Mt)
                a[Mt] = *(const v8s*)(xembT + (size_t)(eA[Mt] >> 1) * KPAD + Ks * 32 + q * 8);
#pragma unroll
            for (int Nt = 0; Nt < 4; ++Nt)
                b[Nt] = *(const v8s*)(W1 + Nt * 16 * KPAD + Ks * 32);
#pragma unroll
            for (int Mt = 0; Mt < 4; ++Mt)
#pragma unroll
                for (int Nt = 0; Nt < 4; ++Nt)
                    acc1[Mt][Nt] = __builtin_amdgcn_mfma_f32_16x16x32_bf16(a[Mt], b[Nt], acc1[Mt][Nt], 0, 0, 0);
        }
        // BN1 + relu -> swizzled LDS
#pragma unroll
        for (int Nt = 0; Nt < 4; ++Nt) {
            int c = Nt * 16 + m;
#pragma unroll
            for (int Mt = 0; Mt < 4; ++Mt)
#pragma unroll
                for (int j = 0; j < 4; ++j) {
                    int item = Mt * 16 + q * 4 + j;
                    float v = fmaxf(fmaf(acc1[Mt][Nt][j], sc1v[Nt], sh1v[Nt]), 0.f);
                    Hl[wid][item][c ^ ((item & 7) << 3)] = f2bf(v);
                }
        }
        // ---- layer 2 (K=64) ----
        v4f acc2[4][4];
#pragma unroll
        for (int a = 0; a < 4; ++a)
#pragma unroll
            for (int c = 0; c < 4; ++c) acc2[a][c] = zero4;
#pragma unroll
        for (int Ks = 0; Ks < 2; ++Ks) {
            v8s a[4], b[4];
#pragma unroll
            for (int Mt = 0; Mt < 4; ++Mt)
                a[Mt] = *(const v8s*)&Hl[wid][Mt * 16 + m][(Ks * 32 + q * 8) ^ ((m & 7) << 3)];
#pragma unroll
            for (int Nt = 0; Nt < 4; ++Nt)
                b[Nt] = *(const v8s*)(W2 + Nt * 16 * 64 + Ks * 32);
#pragma unroll
            for (int Mt = 0; Mt < 4; ++Mt)
#pragma unroll
                for (int Nt = 0; Nt < 4; ++Nt)
                    acc2[Mt][Nt] = __builtin_amdgcn_mfma_f32_16x16x32_bf16(a[Mt], b[Nt], acc2[Mt][Nt], 0, 0, 0);
        }
        // BN2 + relu, * gate weight -> swizzled LDS (reuse)
#pragma unroll
        for (int Mt = 0; Mt < 4; ++Mt) {
            float4 wC = *(const float4*)&lw[k * BB + it0 + Mt * 16 + q * 4];
            float wj[4] = {wC.x, wC.y, wC.z, wC.w};
#pragma unroll
            for (int Nt = 0; Nt < 4; ++Nt) {
                int c = Nt * 16 + m;
#pragma unroll
                for (int j = 0; j < 4; ++j) {
                    int item = Mt * 16 + q * 4 + j;
                    float v = wj[j] * fmaxf(fmaf(acc2[Mt][Nt][j], sc2v[Nt], sh2v[Nt]), 0.f);
                    Hl[wid][item][c ^ ((item & 7) << 3)] = f2bf(v);
                }
            }
        }
        // per-lane: write own row to hs[e][64] (coalesced 16B chunks)
        int eo = lidx[k * BB + it0 + l];
        unsigned short* hrow = hs + (size_t)eo * HID;
#pragma unroll
        for (int u = 0; u < 8; ++u)
            *(v8s*)(hrow + u * 8) = *(const v8s*)&Hl[wid][l][(u * 8) ^ ((l & 7) << 3)];
    }
}

// ---------------- head: sum slots + MFMA (K=64) + BN/relu + dot pw2 ----------------
__global__ __launch_bounds__(256, 2) void k_head(
    const unsigned short* __restrict__ hs, const unsigned short* __restrict__ pw1t,
    const float* __restrict__ scp, const float* __restrict__ shp,
    const float* __restrict__ pw2, const float* __restrict__ pb2,
    float* __restrict__ out)
{
    int tid = threadIdx.x;
    int wid = tid >> 6, l = tid & 63;
    int m = l & 15, q = l >> 4;
    int it0 = blockIdx.x * 256 + wid * 64;
    float scv[4], shv[4], w2v[4];
#pragma unroll
    for (int Nt = 0; Nt < 4; ++Nt) {
        int c = Nt * 16 + m;
        scv[Nt] = scp[c]; shv[Nt] = shp[c]; w2v[Nt] = pw2[c];
    }
    v4f zero4 = {0.f, 0.f, 0.f, 0.f};
    v4f acc[4][4];
#pragma unroll
    for (int a = 0; a < 4; ++a)
#pragma unroll
        for (int c = 0; c < 4; ++c) acc[a][c] = zero4;

#pragma unroll
    for (int Ks = 0; Ks < 2; ++Ks) {
        v8s a[4], b[4];
#pragma unroll
        for (int Mt = 0; Mt < 4; ++Mt) {
            int bi = it0 + Mt * 16 + m;
            const unsigned short* r0 = hs + (size_t)(2 * bi) * HID + Ks * 32 + q * 8;
            v8s u0 = *(const v8s*)r0;
            v8s u1 = *(const v8s*)(r0 + HID);
            v8s av;
#pragma unroll
            for (int e = 0; e < 8; ++e) {
                float f = bf2f((unsigned short)u0[e]) + bf2f((unsigned short)u1[e]);
                av[e] = (short)f2bf(f);
            }
            a[Mt] = av;
        }
#pragma unroll
        for (int Nt = 0; Nt < 4; ++Nt)
            b[Nt] = *(const v8s*)(pw1t + (Nt * 16 + m) * HID + Ks * 32 + q * 8);
#pragma unroll
        for (int Mt = 0; Mt < 4; ++Mt)
#pragma unroll
            for (int Nt = 0; Nt < 4; ++Nt)
                acc[Mt][Nt] = __builtin_amdgcn_mfma_f32_16x16x32_bf16(a[Mt], b[Nt], acc[Mt][Nt], 0, 0, 0);
    }
    float pb2v = pb2[0];
#pragma unroll
    for (int Mt = 0; Mt < 4; ++Mt) {
#pragma unroll
        for (int j = 0; j < 4; ++j) {
            float po = 0.f;
#pragma unroll
            for (int Nt = 0; Nt < 4; ++Nt) {
                float ph = fmaxf(fmaf(acc[Mt][Nt][j], scv[Nt], shv[Nt]), 0.f);
                po = fmaf(ph, w2v[Nt], po);
            }
            po += __shfl_xor(po, 1);
            po += __shfl_xor(po, 2);
            po += __shfl_xor(po, 4);
            po += __shfl_xor(po, 8);
            if (m == 0) out[it0 + Mt * 16 + q * 4 + j] = po + pb2v;
        }
    }
}

extern "C" void kernel_launch(void* const* d_in, const int* in_sizes, int n_in,
                              void* d_out, int out_size, void* d_ws, size_t ws_size,
                              hipStream_t stream) {
    const int*   x     = (const int*)d_in[0];
    const int*   sql   = (const int*)d_in[1];
    const float* itab  = (const float*)d_in[2];
    const float* stab  = (const float*)d_in[3];
    const float* gw1   = (const float*)d_in[4];
    const float* gb1   = (const float*)d_in[5];
    const float* gw2   = (const float*)d_in[6];
    const float* gb2   = (const float*)d_in[7];
    const float* ew1   = (const float*)d_in[8];
    const float* eb1   = (const float*)d_in[9];
    const float* eg1   = (const float*)d_in[10];
    const float* ebe1  = (const float*)d_in[11];
    const float* em1   = (const float*)d_in[12];
    const float* ev1   = (const float*)d_in[13];
    const float* ew2   = (const float*)d_in[14];
    const float* eb2   = (const float*)d_in[15];
    const float* eg2   = (const float*)d_in[16];
    const float* ebe2  = (const float*)d_in[17];
    const float* em2   = (const float*)d_in[18];
    const float* ev2   = (const float*)d_in[19];
    const float* pw1   = (const float*)d_in[20];
    const float* pb1   = (const float*)d_in[21];
    const float* pg    = (const float*)d_in[22];
    const float* pbe   = (const float*)d_in[23];
    const float* pm    = (const float*)d_in[24];
    const float* pv    = (const float*)d_in[25];
    const float* pw2   = (const float*)d_in[26];
    const float* pb2   = (const float*)d_in[27];

    float* wsf = (float*)d_ws;
    int*   wsi = (int*)d_ws;
    int*   gcnt = wsi + OFF_GCNT;
    float* sc1 = wsf + OFF_SC1;
    float* sh1 = wsf + OFF_SH1;
    float* sc2 = wsf + OFF_SC2;
    float* sh2 = wsf + OFF_SH2;
    float* scp = wsf + OFF_SCP;
    float* shp = wsf + OFF_SHP;
    float* imp = wsf + OFF_IMP;
    int*   lidx = wsi + OFF_LIDX;
    float* lw  = wsf + OFF_LW;
    unsigned short* w1t   = (unsigned short*)(wsf + OFF_W1T);
    unsigned short* gw1t  = (unsigned short*)(wsf + OFF_GW1T);
    unsigned short* w2t   = (unsigned short*)(wsf + OFF_W2T);
    unsigned short* pw1t  = (unsigned short*)(wsf + OFF_PW1T);
    unsigned short* xembT = (unsigned short*)(wsf + OFF_XEMB);
    unsigned short* hs    = (unsigned short*)(wsf + OFF_HS);
    float* out = (float*)d_out;

    k_prep<<<1229, 256, 0, stream>>>(ew1, ew2, gw1, pw1,
                                     eb1, eg1, ebe1, em1, ev1,
                                     eb2, eg2, ebe2, em2, ev2,
                                     pb1, pg, pbe, pm, pv,
                                     wsf, gcnt, w1t, gw1t, w2t, pw1t);
    k_gate<<<NBLK_GATE, 256, 0, stream>>>(x, sql, itab, stab, gw1t, gb1, gw2, gb2,
                                          xembT, lidx, lw, gcnt, imp);
    k_loss<<<1, 256, 0, stream>>>(imp, out);
    k_pad<<<16, 64, 0, stream>>>(gcnt, lidx, lw);
    dim3 ge(NBX_EXP, KEXP);
    k_exp<<<ge, 256, 0, stream>>>(xembT, w1t, w2t, sc1, sh1, sc2, sh2,
                                  lidx, lw, gcnt, hs);
    k_head<<<256, 256, 0, stream>>>(hs, pw1t, scp, shp, pw2, pb2, out);
}

// Round 12
// 151.236 us; speedup vs baseline: 1.5093x; 1.5093x over previous
//
#include <hip/hip_runtime.h>
#include <hip/hip_bf16.h>

#define BB 65536
#define NFIELD 20
#define HID 64
#define KEXP 16
#define EPS 1e-5f
#define KPAD 224
#define NKS 7            // 224/32 K-steps
#define NBLK_GATE 1024   // 64 samples per gate block
#define NBX_EXP 40
#define TSTR 228         // gate LDS tile stride (bf16) -> 2-way max bank aliasing

typedef __attribute__((ext_vector_type(8))) short v8s;   // 8 bf16
typedef __attribute__((ext_vector_type(4))) float v4f;

// ---- ws layout (4B element offsets) ----
#define OFF_GCNT 0
#define OFF_SC1 64
#define OFF_SH1 1088
#define OFF_SC2 2112
#define OFF_SH2 3136
#define OFF_SCP 4160
#define OFF_SHP 4224
#define OFF_IMP 4288            // 1024*16 f32
#define OFF_LIDX 20672          // 16*BB int
#define OFF_LW  1069248         // 16*BB f32
#define OFF_W1T 2117824         // 16*64*224 bf16
#define OFF_GW1T 2232512        // 64*224 bf16
#define OFF_W2T 2239680         // 16*64*64 bf16
#define OFF_PW1T 2272448        // 64*64 bf16
#define OFF_XEMB 2274496        // 65537*224 bf16
#define OFF_HS 9614640          // 131073*64 bf16

__device__ __forceinline__ unsigned short f2bf(float f) {
    unsigned int u = __float_as_uint(f);
    unsigned int r = (u + 0x7FFFu + ((u >> 16) & 1u)) >> 16;
    return (unsigned short)r;
}
__device__ __forceinline__ float bf2f(unsigned short u) {
    unsigned int t = ((unsigned int)u) << 16;
    return __uint_as_float(t);
}
__device__ __forceinline__ unsigned int pack2(float a, float b) {
    return (unsigned int)f2bf(a) | ((unsigned int)f2bf(b) << 16);
}

// ---------------- prep: BN folds + bf16 weight transposes + gcnt zero ----------------
__global__ __launch_bounds__(256) void k_prep(
    const float* __restrict__ ew1, const float* __restrict__ ew2,
    const float* __restrict__ gw1, const float* __restrict__ pw1,
    const float* __restrict__ eb1, const float* __restrict__ eg1,
    const float* __restrict__ ebe1, const float* __restrict__ em1,
    const float* __restrict__ ev1,
    const float* __restrict__ eb2, const float* __restrict__ eg2,
    const float* __restrict__ ebe2, const float* __restrict__ em2,
    const float* __restrict__ ev2,
    const float* __restrict__ pb1, const float* __restrict__ pg,
    const float* __restrict__ pbe, const float* __restrict__ pm,
    const float* __restrict__ pv,
    float* __restrict__ wsf, int* __restrict__ gcnt,
    unsigned short* __restrict__ w1t, unsigned short* __restrict__ gw1t,
    unsigned short* __restrict__ w2t, unsigned short* __restrict__ pw1t)
{
    int gid = blockIdx.x * 256 + threadIdx.x;
    if (gid < 229376) {               // W1T[k][c][t] = ew1[k][t][c]
        int k = gid / 14336, r = gid % 14336, c = r / KPAD, t = r % KPAD;
        w1t[gid] = (t < 200) ? f2bf(ew1[((size_t)k * 200 + t) * HID + c]) : 0;
    } else if (gid < 229376 + 14336) { // gw1T[c][t]
        int g2 = gid - 229376; int c = g2 / KPAD, t = g2 % KPAD;
        gw1t[g2] = (t < 200) ? f2bf(gw1[t * HID + c]) : 0;
    } else if (gid < 243712 + 65536) { // W2T[k][g][i] = ew2[k][i][g]
        int g2 = gid - 243712; int k = g2 / 4096, r = g2 % 4096, g = r / 64, i = r % 64;
        w2t[g2] = f2bf(ew2[((size_t)k * 64 + i) * 64 + g]);
    } else if (gid < 309248 + 4096) {  // PW1T[g][i] = pw1[i][g]
        int g2 = gid - 309248; int g = g2 / 64, i = g2 % 64;
        pw1t[g2] = f2bf(pw1[i * 64 + g]);
    } else if (gid < 313344 + 1024) {
        int t = gid - 313344;
        float rs1 = rsqrtf(ev1[t] + EPS) * eg1[t];
        wsf[OFF_SC1 + t] = rs1;
        wsf[OFF_SH1 + t] = fmaf(eb1[t] - em1[t], rs1, ebe1[t]);
        float rs2 = rsqrtf(ev2[t] + EPS) * eg2[t];
        wsf[OFF_SC2 + t] = rs2;
        wsf[OFF_SH2 + t] = fmaf(eb2[t] - em2[t], rs2, ebe2[t]);
    } else if (gid < 314368 + 64) {
        int t = gid - 314368;
        float rs = rsqrtf(pv[t] + EPS) * pg[t];
        wsf[OFF_SCP + t] = rs;
        wsf[OFF_SHP + t] = fmaf(pb1[t] - pm[t], rs, pbe[t]);
    } else if (gid < 314432 + 16) {
        gcnt[gid - 314432] = 0;
    }
}

// ---------------- fused gather+gate: x->xembT, sql->LDS->MFMA->softmax/top2/list ----------------
__global__ __launch_bounds__(256) void k_gate(
    const int* __restrict__ x, const int* __restrict__ sql,
    const float* __restrict__ itab, const float* __restrict__ stab,
    const unsigned short* __restrict__ gw1t,
    const float* __restrict__ gb1, const float* __restrict__ gw2,
    const float* __restrict__ gb2,
    unsigned short* __restrict__ xembT,
    int* __restrict__ lidx, float* __restrict__ lw,
    int* __restrict__ gcnt, float* __restrict__ imp_part)
{
    __shared__ unsigned short tile[64][TSTR];       // 29184 B; Hg overlaid after MFMA
    __shared__ float s_imp[KEXP];
    __shared__ int s_cnt[KEXP];
    __shared__ int s_base[KEXP];
    unsigned short (*Hg)[80] = (unsigned short (*)[80])&tile[0][0];
    int tid = threadIdx.x;
    int wid = tid >> 6, l = tid & 63;
    int m = l & 15, q = l >> 4;
    int b0 = blockIdx.x * 64;

    if (tid < KEXP) { s_imp[tid] = 0.f; s_cnt[tid] = 0; }
    // zero pad cols 200..223 of sql LDS tile
    for (int t = tid; t < 64 * 12; t += 256) {
        int r = t / 12, c2 = t % 12;
        *(unsigned int*)&tile[r][200 + 2 * c2] = 0;
    }
    // zero xembT tail cols 200..223 (bytes 400..447 of each 448B row)
    {
        uint4 z4 = {0u, 0u, 0u, 0u};
        if (tid < 192) {
            int row = tid / 3, j = tid % 3;
            *(uint4*)((char*)(xembT + (size_t)(b0 + row) * KPAD) + 400 + 16 * j) = z4;
        }
    }
    // gather 64*20 sql rows -> LDS and 64*20 x rows -> xembT (10 rows in flight/thread)
#pragma unroll
    for (int rr = 0; rr < 5; ++rr) {
        int r = tid + rr * 256;
        int lb = r / NFIELD, f = r % NFIELD;
        int sidx = sql[(size_t)(b0 + lb) * NFIELD + f];
        int xidx = x[(size_t)(b0 + lb) * NFIELD + f];
        const float* srow = stab + (size_t)sidx * 10;
        const float* xrow = itab + (size_t)xidx * 10;
        float2 s0 = *(const float2*)(srow + 0);
        float2 s1 = *(const float2*)(srow + 2);
        float2 s2 = *(const float2*)(srow + 4);
        float2 s3 = *(const float2*)(srow + 6);
        float2 s4 = *(const float2*)(srow + 8);
        float2 x0 = *(const float2*)(xrow + 0);
        float2 x1 = *(const float2*)(xrow + 2);
        float2 x2 = *(const float2*)(xrow + 4);
        float2 x3 = *(const float2*)(xrow + 6);
        float2 x4 = *(const float2*)(xrow + 8);
        unsigned int* lrow = (unsigned int*)&tile[lb][f * 10];
        lrow[0] = pack2(s0.x, s0.y);
        lrow[1] = pack2(s1.x, s1.y);
        lrow[2] = pack2(s2.x, s2.y);
        lrow[3] = pack2(s3.x, s3.y);
        lrow[4] = pack2(s4.x, s4.y);
        unsigned int* grow = (unsigned int*)(xembT + (size_t)(b0 + lb) * KPAD + f * 10);
        grow[0] = pack2(x0.x, x0.y);
        grow[1] = pack2(x1.x, x1.y);
        grow[2] = pack2(x2.x, x2.y);
        grow[3] = pack2(x3.x, x3.y);
        grow[4] = pack2(x4.x, x4.y);
    }
    __syncthreads();

    // MFMA: 64 samples x 16 cols (this wave) x K=224
    v4f zero4 = {0.f, 0.f, 0.f, 0.f};
    v4f acc[4];
#pragma unroll
    for (int a = 0; a < 4; ++a) acc[a] = zero4;
    const unsigned short* Bb = gw1t + (wid * 16 + m) * KPAD + q * 8;
#pragma unroll
    for (int Ks = 0; Ks < NKS; ++Ks) {
        v8s bv = *(const v8s*)(Bb + Ks * 32);
        v8s a[4];
#pragma unroll
        for (int Mt = 0; Mt < 4; ++Mt)
            a[Mt] = *(const v8s*)&tile[Mt * 16 + m][Ks * 32 + q * 8];
#pragma unroll
        for (int Mt = 0; Mt < 4; ++Mt)
            acc[Mt] = __builtin_amdgcn_mfma_f32_16x16x32_bf16(a[Mt], bv, acc[Mt], 0, 0, 0);
    }
    __syncthreads();   // all tile reads done before Hg overlay

    int c = wid * 16 + m;
    float bias = gb1[c];
#pragma unroll
    for (int Mt = 0; Mt < 4; ++Mt)
#pragma unroll
        for (int j = 0; j < 4; ++j) {
            int item = Mt * 16 + q * 4 + j;
            float v = fmaxf(acc[Mt][j] + bias, 0.f);
            Hg[item][c ^ ((item & 7) << 3)] = f2bf(v);
        }
    __syncthreads();   // Hg ready

    if (wid == 0) {
        float z[KEXP];
#pragma unroll
        for (int j = 0; j < KEXP; ++j) z[j] = gb2[j];
#pragma unroll
        for (int u = 0; u < 8; ++u) {
            v8s hv = *(const v8s*)&Hg[l][(u * 8) ^ ((l & 7) << 3)];
#pragma unroll
            for (int e = 0; e < 8; ++e) {
                int h = u * 8 + e;
                float g = bf2f((unsigned short)hv[e]);
#pragma unroll
                for (int j = 0; j < KEXP; ++j) z[j] = fmaf(g, gw2[h * KEXP + j], z[j]);
            }
        }
        float mm = z[0];
#pragma unroll
        for (int j = 1; j < KEXP; ++j) mm = fmaxf(mm, z[j]);
        float s = 0.f;
#pragma unroll
        for (int j = 0; j < KEXP; ++j) s += expf(z[j] - mm);
        int i0 = 0; float m0 = z[0];
#pragma unroll
        for (int j = 1; j < KEXP; ++j) if (z[j] > m0) { m0 = z[j]; i0 = j; }
        int i1 = (i0 == 0) ? 1 : 0; float m1 = -3.4e38f;
#pragma unroll
        for (int j = 0; j < KEXP; ++j) if (j != i0 && z[j] > m1) { m1 = z[j]; i1 = j; }
        float v0 = expf(m0 - mm) / s, v1 = expf(m1 - mm) / s;
        float inv = 1.f / (v0 + v1 + 1e-9f);
        float w0 = v0 * inv, w1 = v1 * inv;

        atomicAdd(&s_imp[i0], w0);
        atomicAdd(&s_imp[i1], w1);
        int o0 = atomicAdd(&s_cnt[i0], 1);
        int o1 = atomicAdd(&s_cnt[i1], 1);
        __syncthreads();   // wave0 atomics visible
        if (l < KEXP) s_base[l] = atomicAdd(&gcnt[l], s_cnt[l]);
        __syncthreads();
        int b = b0 + l;
        int p0 = i0 * BB + s_base[i0] + o0;
        lidx[p0] = (b << 1);     lw[p0] = w0;
        int p1 = i1 * BB + s_base[i1] + o1;
        lidx[p1] = (b << 1) | 1; lw[p1] = w1;
    } else {
        __syncthreads();
        __syncthreads();
    }
    __syncthreads();
    if (tid < KEXP) imp_part[blockIdx.x * KEXP + tid] = s_imp[tid];
}

// ---------------- pad each expert list to multiple of 64 with benign entries ----------------
__global__ void k_pad(const int* __restrict__ gcnt, int* __restrict__ lidx,
                      float* __restrict__ lw)
{
    int k = blockIdx.x;
    int n = gcnt[k];
    int ne = (n + 63) & ~63;
    for (int i = n + threadIdx.x; i < ne; i += 64) {
        lidx[k * BB + i] = 2 * BB;   // dedicated pad row
        lw[k * BB + i] = 0.f;
    }
}

// ---------------- loss ----------------
__global__ __launch_bounds__(256) void k_loss(const float* __restrict__ imp_part,
                                              float* __restrict__ out)
{
    __shared__ double sred[16][17];
    __shared__ double simp[KEXP];
    int tid = threadIdx.x;
    int j = tid & 15, g = tid >> 4;
    double s = 0.0;
    for (int blk = g; blk < NBLK_GATE; blk += 16) s += (double)imp_part[blk * KEXP + j];
    sred[g][j] = s;
    __syncthreads();
    if (tid < KEXP) {
        double t = 0.0;
#pragma unroll
        for (int gg = 0; gg < 16; ++gg) t += sred[gg][tid];
        simp[tid] = t;
    }
    __syncthreads();
    if (tid == 0) {
        double mean = 0.0;
        for (int jj = 0; jj < KEXP; ++jj) mean += simp[jj];
        mean /= KEXP;
        double var = 0.0;
        for (int jj = 0; jj < KEXP; ++jj) { double d = simp[jj] - mean; var += d * d; }
        var /= KEXP;
        out[BB] = (float)(var / (mean * mean + 1e-10));
    }
}

// ---------------- fused expert: MFMA L1 -> LDS -> MFMA L2 -> hs (bf16) ----------------
__global__ __launch_bounds__(256, 2) void k_exp(
    const unsigned short* __restrict__ xembT,
    const unsigned short* __restrict__ w1t, const unsigned short* __restrict__ w2t,
    const float* __restrict__ sc1, const float* __restrict__ sh1,
    const float* __restrict__ sc2, const float* __restrict__ sh2,
    const int* __restrict__ lidx, const float* __restrict__ lw,
    const int* __restrict__ gcnt, unsigned short* __restrict__ hs)
{
    __shared__ unsigned short Hl[4][64][80];   // 40960 B, bank-rotating rows
    int k = blockIdx.y;
    int tid = threadIdx.x;
    int wid = tid >> 6, l = tid & 63;
    int m = l & 15, q = l >> 4;
    int n = gcnt[k];
    int ne = (n + 63) & ~63;
    const unsigned short* W1 = w1t + (size_t)k * 64 * KPAD + m * KPAD + q * 8;
    const unsigned short* W2 = w2t + (size_t)k * 64 * 64 + m * 64 + q * 8;
    float sc1v[4], sh1v[4], sc2v[4], sh2v[4];
#pragma unroll
    for (int Nt = 0; Nt < 4; ++Nt) {
        int c = Nt * 16 + m;
        sc1v[Nt] = sc1[k * HID + c]; sh1v[Nt] = sh1[k * HID + c];
        sc2v[Nt] = sc2[k * HID + c]; sh2v[Nt] = sh2[k * HID + c];
    }
    v4f zero4 = {0.f, 0.f, 0.f, 0.f};

    for (int it0 = (blockIdx.x * 4 + wid) * 64; it0 < ne; it0 += NBX_EXP * 256) {
        // ---- layer 1 ----
        int eA[4];
#pragma unroll
        for (int Mt = 0; Mt < 4; ++Mt) eA[Mt] = lidx[k * BB + it0 + Mt * 16 + m];
        v4f acc1[4][4];
#pragma unroll
        for (int a = 0; a < 4; ++a)
#pragma unroll
            for (int c = 0; c < 4; ++c) acc1[a][c] = zero4;
#pragma unroll
        for (int Ks = 0; Ks < NKS; ++Ks) {
            v8s a[4], b[4];
#pragma unroll
            for (int Mt = 0; Mt < 4; ++Mt)
                a[Mt] = *(const v8s*)(xembT + (size_t)(eA[Mt] >> 1) * KPAD + Ks * 32 + q * 8);
#pragma unroll
            for (int Nt = 0; Nt < 4; ++Nt)
                b[Nt] = *(const v8s*)(W1 + Nt * 16 * KPAD + Ks * 32);
#pragma unroll
            for (int Mt = 0; Mt < 4; ++Mt)
#pragma unroll
                for (int Nt = 0; Nt < 4; ++Nt)
                    acc1[Mt][Nt] = __builtin_amdgcn_mfma_f32_16x16x32_bf16(a[Mt], b[Nt], acc1[Mt][Nt], 0, 0, 0);
        }
        // BN1 + relu -> swizzled LDS
#pragma unroll
        for (int Nt = 0; Nt < 4; ++Nt) {
            int c = Nt * 16 + m;
#pragma unroll
            for (int Mt = 0; Mt < 4; ++Mt)
#pragma unroll
                for (int j = 0; j < 4; ++j) {
                    int item = Mt * 16 + q * 4 + j;
                    float v = fmaxf(fmaf(acc1[Mt][Nt][j], sc1v[Nt], sh1v[Nt]), 0.f);
                    Hl[wid][item][c ^ ((item & 7) << 3)] = f2bf(v);
                }
        }
        // ---- layer 2 (K=64) ----
        v4f acc2[4][4];
#pragma unroll
        for (int a = 0; a < 4; ++a)
#pragma unroll
            for (int c = 0; c < 4; ++c) acc2[a][c] = zero4;
#pragma unroll
        for (int Ks = 0; Ks < 2; ++Ks) {
            v8s a[4], b[4];
#pragma unroll
            for (int Mt = 0; Mt < 4; ++Mt)
                a[Mt] = *(const v8s*)&Hl[wid][Mt * 16 + m][(Ks * 32 + q * 8) ^ ((m & 7) << 3)];
#pragma unroll
            for (int Nt = 0; Nt < 4; ++Nt)
                b[Nt] = *(const v8s*)(W2 + Nt * 16 * 64 + Ks * 32);
#pragma unroll
            for (int Mt = 0; Mt < 4; ++Mt)
#pragma unroll
                for (int Nt = 0; Nt < 4; ++Nt)
                    acc2[Mt][Nt] = __builtin_amdgcn_mfma_f32_16x16x32_bf16(a[Mt], b[Nt], acc2[Mt][Nt], 0, 0, 0);
        }
        // BN2 + relu, * gate weight -> swizzled LDS (reuse)
#pragma unroll
        for (int Mt = 0; Mt < 4; ++Mt) {
            float4 wC = *(const float4*)&lw[k * BB + it0 + Mt * 16 + q * 4];
            float wj[4] = {wC.x, wC.y, wC.z, wC.w};
#pragma unroll
            for (int Nt = 0; Nt < 4; ++Nt) {
                int c = Nt * 16 + m;
#pragma unroll
                for (int j = 0; j < 4; ++j) {
                    int item = Mt * 16 + q * 4 + j;
                    float v = wj[j] * fmaxf(fmaf(acc2[Mt][Nt][j], sc2v[Nt], sh2v[Nt]), 0.f);
                    Hl[wid][item][c ^ ((item & 7) << 3)] = f2bf(v);
                }
            }
        }
        // per-lane: write own row to hs[e][64] (coalesced 16B chunks)
        int eo = lidx[k * BB + it0 + l];
        unsigned short* hrow = hs + (size_t)eo * HID;
#pragma unroll
        for (int u = 0; u < 8; ++u)
            *(v8s*)(hrow + u * 8) = *(const v8s*)&Hl[wid][l][(u * 8) ^ ((l & 7) << 3)];
    }
}

// ---------------- head: sum slots + MFMA (K=64) + BN/relu + dot pw2 ----------------
__global__ __launch_bounds__(256, 2) void k_head(
    const unsigned short* __restrict__ hs, const unsigned short* __restrict__ pw1t,
    const float* __restrict__ scp, const float* __restrict__ shp,
    const float* __restrict__ pw2, const float* __restrict__ pb2,
    float* __restrict__ out)
{
    int tid = threadIdx.x;
    int wid = tid >> 6, l = tid & 63;
    int m = l & 15, q = l >> 4;
    int it0 = blockIdx.x * 256 + wid * 64;
    float scv[4], shv[4], w2v[4];
#pragma unroll
    for (int Nt = 0; Nt < 4; ++Nt) {
        int c = Nt * 16 + m;
        scv[Nt] = scp[c]; shv[Nt] = shp[c]; w2v[Nt] = pw2[c];
    }
    v4f zero4 = {0.f, 0.f, 0.f, 0.f};
    v4f acc[4][4];
#pragma unroll
    for (int a = 0; a < 4; ++a)
#pragma unroll
        for (int c = 0; c < 4; ++c) acc[a][c] = zero4;

#pragma unroll
    for (int Ks = 0; Ks < 2; ++Ks) {
        v8s a[4], b[4];
#pragma unroll
        for (int Mt = 0; Mt < 4; ++Mt) {
            int bi = it0 + Mt * 16 + m;
            const unsigned short* r0 = hs + (size_t)(2 * bi) * HID + Ks * 32 + q * 8;
            v8s u0 = *(const v8s*)r0;
            v8s u1 = *(const v8s*)(r0 + HID);
            v8s av;
#pragma unroll
            for (int e = 0; e < 8; ++e) {
                float f = bf2f((unsigned short)u0[e]) + bf2f((unsigned short)u1[e]);
                av[e] = (short)f2bf(f);
            }
            a[Mt] = av;
        }
#pragma unroll
        for (int Nt = 0; Nt < 4; ++Nt)
            b[Nt] = *(const v8s*)(pw1t + (Nt * 16 + m) * HID + Ks * 32 + q * 8);
#pragma unroll
        for (int Mt = 0; Mt < 4; ++Mt)
#pragma unroll
            for (int Nt = 0; Nt < 4; ++Nt)
                acc[Mt][Nt] = __builtin_amdgcn_mfma_f32_16x16x32_bf16(a[Mt], b[Nt], acc[Mt][Nt], 0, 0, 0);
    }
    float pb2v = pb2[0];
#pragma unroll
    for (int Mt = 0; Mt < 4; ++Mt) {
#pragma unroll
        for (int j = 0; j < 4; ++j) {
            float po = 0.f;
#pragma unroll
            for (int Nt = 0; Nt < 4; ++Nt) {
                float ph = fmaxf(fmaf(acc[Mt][Nt][j], scv[Nt], shv[Nt]), 0.f);
                po = fmaf(ph, w2v[Nt], po);
            }
            po += __shfl_xor(po, 1);
            po += __shfl_xor(po, 2);
            po += __shfl_xor(po, 4);
            po += __shfl_xor(po, 8);
            if (m == 0) out[it0 + Mt * 16 + q * 4 + j] = po + pb2v;
        }
    }
}

extern "C" void kernel_launch(void* const* d_in, const int* in_sizes, int n_in,
                              void* d_out, int out_size, void* d_ws, size_t ws_size,
                              hipStream_t stream) {
    const int*   x     = (const int*)d_in[0];
    const int*   sql   = (const int*)d_in[1];
    const float* itab  = (const float*)d_in[2];
    const float* stab  = (const float*)d_in[3];
    const float* gw1   = (const float*)d_in[4];
    const float* gb1   = (const float*)d_in[5];
    const float* gw2   = (const float*)d_in[6];
    const float* gb2   = (const float*)d_in[7];
    const float* ew1   = (const float*)d_in[8];
    const float* eb1   = (const float*)d_in[9];
    const float* eg1   = (const float*)d_in[10];
    const float* ebe1  = (const float*)d_in[11];
    const float* em1   = (const float*)d_in[12];
    const float* ev1   = (const float*)d_in[13];
    const float* ew2   = (const float*)d_in[14];
    const float* eb2   = (const float*)d_in[15];
    const float* eg2   = (const float*)d_in[16];
    const float* ebe2  = (const float*)d_in[17];
    const float* em2   = (const float*)d_in[18];
    const float* ev2   = (const float*)d_in[19];
    const float* pw1   = (const float*)d_in[20];
    const float* pb1   = (const float*)d_in[21];
    const float* pg    = (const float*)d_in[22];
    const float* pbe   = (const float*)d_in[23];
    const float* pm    = (const float*)d_in[24];
    const float* pv    = (const float*)d_in[25];
    const float* pw2   = (const float*)d_in[26];
    const float* pb2   = (const float*)d_in[27];

    float* wsf = (float*)d_ws;
    int*   wsi = (int*)d_ws;
    int*   gcnt = wsi + OFF_GCNT;
    float* sc1 = wsf + OFF_SC1;
    float* sh1 = wsf + OFF_SH1;
    float* sc2 = wsf + OFF_SC2;
    float* sh2 = wsf + OFF_SH2;
    float* scp = wsf + OFF_SCP;
    float* shp = wsf + OFF_SHP;
    float* imp = wsf + OFF_IMP;
    int*   lidx = wsi + OFF_LIDX;
    float* lw  = wsf + OFF_LW;
    unsigned short* w1t   = (unsigned short*)(wsf + OFF_W1T);
    unsigned short* gw1t  = (unsigned short*)(wsf + OFF_GW1T);
    unsigned short* w2t   = (unsigned short*)(wsf + OFF_W2T);
    unsigned short* pw1t  = (unsigned short*)(wsf + OFF_PW1T);
    unsigned short* xembT = (unsigned short*)(wsf + OFF_XEMB);
    unsigned short* hs    = (unsigned short*)(wsf + OFF_HS);
    float* out = (float*)d_out;

    k_prep<<<1229, 256, 0, stream>>>(ew1, ew2, gw1, pw1,
                                     eb1, eg1, ebe1, em1, ev1,
                                     eb2, eg2, ebe2, em2, ev2,
                                     pb1, pg, pbe, pm, pv,
                                     wsf, gcnt, w1t, gw1t, w2t, pw1t);
    k_gate<<<NBLK_GATE, 256, 0, stream>>>(x, sql, itab, stab, gw1t, gb1, gw2, gb2,
                                          xembT, lidx, lw, gcnt, imp);
    k_loss<<<1, 256, 0, stream>>>(imp, out);
    k_pad<<<16, 64, 0, stream>>>(gcnt, lidx, lw);
    dim3 ge(NBX_EXP, KEXP);
    k_exp<<<ge, 256, 0, stream>>>(xembT, w1t, w2t, sc1, sh1, sc2, sh2,
                                  lidx, lw, gcnt, hs);
    k_head<<<256, 256, 0, stream>>>(hs, pw1t, scp, shp, pw2, pb2, out);
}